// Round 11
// baseline (15734.422 us; speedup 1.0000x reference)
//
#include <hip/hip_runtime.h>
#include <stdint.h>

#define NEG_INF -100000000.0f

typedef unsigned short u16;
typedef unsigned long long u64;
typedef __attribute__((ext_vector_type(8))) short v8s;
typedef __attribute__((ext_vector_type(4))) short v4s;
typedef __attribute__((ext_vector_type(4))) float v4f;

__device__ __forceinline__ float bf2f(u16 h){ return __uint_as_float(((unsigned)h)<<16); }
__device__ __forceinline__ u16 f2bf(float f){
  unsigned u = __float_as_uint(f);
  u = u + 0x7fffu + ((u>>16)&1u);
  return (u16)(u>>16);
}
__device__ __forceinline__ float sigm(float x){ return 1.0f/(1.0f+__expf(-x)); }
__device__ __forceinline__ float ftanh(float x){
  x = fminf(15.0f, fmaxf(-15.0f, x));
  float e = __expf(2.0f*x);
  return (e-1.0f)/(e+1.0f);
}

// write-through (coherence-point) 16B h store; consumer loads are PLAIN
__device__ __forceinline__ void store_h16(u16* p, u64 a, u64 b){
  __hip_atomic_store((u64*)p,     a, __ATOMIC_RELAXED, __HIP_MEMORY_SCOPE_AGENT);
  __hip_atomic_store((u64*)(p+4), b, __ATOMIC_RELAXED, __HIP_MEMORY_SCOPE_AGENT);
}

// ---------------------------------------------------------------------------
// Fused f32 -> bf16 arena conversion
// ---------------------------------------------------------------------------
struct CvtTab {
  const float* src[31];
  unsigned off[31];
  unsigned n[31];
  unsigned total;
};

__global__ __launch_bounds__(256) void cvt_all(CvtTab tab, u16* __restrict__ arena){
  unsigned e0 = (blockIdx.x*256u + threadIdx.x)*8u;
  if (e0 >= tab.total) return;
  int s = 0;
#pragma unroll 1
  for (int i = 1; i < 31; ++i) if (e0 >= tab.off[i]) s = i;
  unsigned rel = e0 - tab.off[s];
  const float* sp = tab.src[s] + rel;
  unsigned nn = tab.n[s];
  union { u16 h[8]; v8s v; } o;
  if (rel + 8 <= nn) {
    float4 a = *(const float4*)sp;
    float4 b = *(const float4*)(sp+4);
    o.h[0]=f2bf(a.x); o.h[1]=f2bf(a.y); o.h[2]=f2bf(a.z); o.h[3]=f2bf(a.w);
    o.h[4]=f2bf(b.x); o.h[5]=f2bf(b.y); o.h[6]=f2bf(b.z); o.h[7]=f2bf(b.w);
  } else {
#pragma unroll
    for (int k = 0; k < 8; ++k) o.h[k] = (rel + k < nn) ? f2bf(sp[k]) : (u16)0;
  }
  *(v8s*)(arena + e0) = o.v;
}

// ---------------------------------------------------------------------------
// Generic bf16 GEMM: C[M][N] = A[M][K] @ B[N][K]^T (+bias1+bias2)(+tanh)(+C)
// ---------------------------------------------------------------------------
#define GF_OUTBF16 1
#define GF_TANH    2
#define GF_ACCUM   4

__global__ __launch_bounds__(256) void gemm_bf16(
    const u16* __restrict__ A, long long lda,
    const u16* __restrict__ B,
    const u16* __restrict__ bias1, const u16* __restrict__ bias2,
    void* __restrict__ Cout, long long ldc,
    int M, int Nn, int K, int flags)
{
  __shared__ u16 As[8192];
  __shared__ u16 Bs[8192];
  int tid = threadIdx.x;
  int lane = tid & 63, w = tid >> 6;
  int wm = w >> 1, wn = w & 1;
  int bm = blockIdx.x * 128, bn = blockIdx.y * 128;

  v4f acc[4][4];
#pragma unroll
  for (int i=0;i<4;++i)
#pragma unroll
    for (int j=0;j<4;++j) acc[i][j] = (v4f){0.f,0.f,0.f,0.f};

#pragma unroll 1
  for (int ko = 0; ko < K; ko += 64) {
    __syncthreads();
#pragma unroll
    for (int it = 0; it < 8; ++it) {
      int c = tid + 256*it;
      int half = c >> 10;
      int cc = c & 1023;
      int r = cc >> 3;
      int kcb = cc & 7;
      const u16* src;
      if (half == 0) {
        int row = min(bm + r, M-1);
        src = A + (size_t)row*(size_t)lda + ko + (kcb<<3);
      } else {
        int row = min(bn + r, Nn-1);
        src = B + (size_t)row*(size_t)K + ko + (kcb<<3);
      }
      v8s v = *(const v8s*)src;
      char* base = (char*)(half ? Bs : As);
      *(v8s*)(base + (r<<7) + ((kcb<<4) ^ ((r&7)<<4))) = v;
    }
    __syncthreads();
#pragma unroll
    for (int ks = 0; ks < 2; ++ks) {
      v8s af[4], bfr[4];
#pragma unroll
      for (int mt=0; mt<4; ++mt) {
        int r = wm*64 + mt*16 + (lane & 15);
        int kb = (ks<<6) + ((lane>>4)<<4);
        af[mt] = *(const v8s*)((const char*)As + (r<<7) + (kb ^ ((r&7)<<4)));
      }
#pragma unroll
      for (int nt=0; nt<4; ++nt) {
        int r = wn*64 + nt*16 + (lane & 15);
        int kb = (ks<<6) + ((lane>>4)<<4);
        bfr[nt] = *(const v8s*)((const char*)Bs + (r<<7) + (kb ^ ((r&7)<<4)));
      }
#pragma unroll
      for (int mt=0; mt<4; ++mt)
#pragma unroll
        for (int nt=0; nt<4; ++nt)
          acc[mt][nt] = __builtin_amdgcn_mfma_f32_16x16x32_bf16(af[mt], bfr[nt], acc[mt][nt], 0,0,0);
    }
  }

#pragma unroll
  for (int mt=0; mt<4; ++mt) {
#pragma unroll
    for (int nt=0; nt<4; ++nt) {
      int col = bn + wn*64 + nt*16 + (lane&15);
      if (col >= Nn) continue;
      float b = 0.f;
      if (bias1) b += bf2f(bias1[col]);
      if (bias2) b += bf2f(bias2[col]);
#pragma unroll
      for (int r=0; r<4; ++r) {
        int row = bm + wm*64 + mt*16 + ((lane>>4)<<2) + r;
        if (row >= M) continue;
        float v = acc[mt][nt][r] + b;
        if (flags & GF_ACCUM) v += ((float*)Cout)[(size_t)row*(size_t)ldc + col];
        if (flags & GF_TANH) v = ftanh(v);
        if (flags & GF_OUTBF16) ((u16*)Cout)[(size_t)row*(size_t)ldc + col] = f2bf(v);
        else                    ((float*)Cout)[(size_t)row*(size_t)ldc + col] = v;
      }
    }
  }
}

// ---------------------------------------------------------------------------
// Persistent bidirectional LSTM scan, TWO interleaved batch-group chains per
// block. 128 blocks = dir(2) x ug(64: 8 units). Chains c=0,1 are the two
// 32-batch groups of this dir: same pinned weights serve both; while chain A
// waits on its LLC round-trips (h-load, store-drain, progress), chain B's
// work fills the pipe. Waves: kh = w>>1 (K-half), gp = w&1 (gate pair);
// MFMA N packs 2 gates x 8 units in one fragment (row an = (gp*2+(an>>3),
// an&7)). Per-loop: joint wave-wide poll of both groups' progress (lanes
// 0-31 = A, 32-63 = B) -> chain A {h/x loads, MFMA, glds0-exchange, sync,
// pw, wave-local hlds0, WT-store} -> chain B {same, glds1} -> one vmcnt(0)
// drain -> sync -> post both progress words. 3 syncs/loop.
// Coherence: write-through relaxed-atomic h stores; plain consumer loads
// (each line written once, read only after producer progress seen).
// ---------------------------------------------------------------------------
template<int LAYER>
__global__ __launch_bounds__(256, 1) void lstm_scan(
    const u16* __restrict__ xsrc,      // L0: embW ; L1: h0
    const int* __restrict__ Xidx,      // L0 only
    const u16* __restrict__ Wih_f, const u16* __restrict__ Wih_b,
    const u16* __restrict__ Whh_f, const u16* __restrict__ Whh_b,
    const u16* __restrict__ bih_f, const u16* __restrict__ bhh_f,
    const u16* __restrict__ bih_b, const u16* __restrict__ bhh_b,
    u16* __restrict__ hbuf,            // [64][512][1024] layer output
    unsigned* __restrict__ prog)       // 4 groups x 64 u32
{
  constexpr int KX  = (LAYER==0) ? 128 : 1024;
  constexpr int NKC = KX/64;                 // x k-chunks per K-half (2 / 16)
  __shared__ float glds[2][8*32*10];         // per chain: [kh*4+gate][n(32)][u8+2]
  __shared__ u16   hlds[2][256];             // per chain: [n(32)][u(8)]

  const int tid = threadIdx.x, lane = tid & 63, w = tid >> 6;
  const int kh = w >> 1, gp = w & 1;
  const int dir = blockIdx.x >> 6, ug = blockIdx.x & 63;
  const int an = lane & 15, hi = lane >> 4, ak = hi << 3;
  const u16* Wih = dir ? Wih_b : Wih_f;
  const u16* Whh = dir ? Whh_b : Whh_f;
  const int gidA = dir*2, gidB = dir*2 + 1;
  unsigned* progA = prog + gidA*64;
  unsigned* progB = prog + gidB*64;

  const int g = 2*gp + (an>>3);              // gate for this lane's B-row
  const size_t jrow = (size_t)g*512 + ug*8 + (an&7);

  // ---- weights pinned in VGPRs ----
  v8s wih_reg[NKC];
  {
    const u16* wp = Wih + jrow*KX + kh*(KX/2);
#pragma unroll
    for (int kc = 0; kc < NKC; ++kc) {
      wih_reg[kc] = *(const v8s*)(wp + kc*32 + ak);
      asm volatile("" : "+v"(wih_reg[kc]));
    }
  }
  v8s whh_reg[8];
  {
    const u16* wp = Whh + jrow*512 + kh*256;
#pragma unroll
    for (int kc = 0; kc < 8; ++kc) {
      whh_reg[kc] = *(const v8s*)(wp + kc*32 + ak);
      asm volatile("" : "+v"(whh_reg[kc]));
    }
  }

  const int u_pw = tid & 7, n2 = tid >> 3;   // pointwise: unit u_pw, row n2 (0..31)
  const int uj_pw = ug*8 + u_pw;
  float bsum[4];
  {
    const u16* bi = dir ? bih_b : bih_f;
    const u16* bh = dir ? bhh_b : bhh_f;
#pragma unroll
    for (int q = 0; q < 4; ++q)
      bsum[q] = bf2f(bi[q*512 + uj_pw]) + bf2f(bh[q*512 + uj_pw]);
  }
  float creg[2] = {0.f, 0.f};

  // ---- L0: x prefetch registers (both chains), step 0 ----
  constexpr int XC = (LAYER==0) ? 2 : 1;
  v8s xreg[2][2][XC];
  if constexpr (LAYER == 0) {
    const int t0 = dir ? 511 : 0;
#pragma unroll
    for (int c = 0; c < 2; ++c)
#pragma unroll
      for (int mt = 0; mt < 2; ++mt) {
        int ng = c*32 + mt*16 + an;
        const u16* xr = xsrc + (size_t)Xidx[ng*512 + t0]*128 + kh*64;
#pragma unroll
        for (int kc = 0; kc < 2; ++kc) xreg[c][mt][kc] = *(const v8s*)(xr + kc*32 + ak);
      }
  }

  for (int step = 0; step < 512; ++step) {
    const int t     = dir ? (511 - step) : step;
    const int tprev = dir ? (t + 1) : (t - 1);

    // ---- joint wave-wide poll: lanes 0-31 chain A, 32-63 chain B ----
    if (step > 0) {
      const u64* pl = (lane < 32) ? ((const u64*)progA + lane)
                                  : ((const u64*)progB + (lane - 32));
      int spins = 0;
      for (;;) {
        u64 v = __hip_atomic_load(pl, __ATOMIC_RELAXED, __HIP_MEMORY_SCOPE_AGENT);
        bool ok = ((unsigned)v >= (unsigned)step) && ((unsigned)(v>>32) >= (unsigned)step);
        if (__all(ok)) break;
        if (++spins > 4) __builtin_amdgcn_s_sleep(1);
      }
      asm volatile("" ::: "memory");
    }

    // ================= two chains, unrolled =================
#pragma unroll
    for (int c = 0; c < 2; ++c) {
      v4f acc[2];
      acc[0] = (v4f){0,0,0,0}; acc[1] = (v4f){0,0,0,0};

      if (step > 0) {
        // issue h loads; x (regs or loads) covers part of their flight
        v8s haf[2][8];
#pragma unroll
        for (int mt = 0; mt < 2; ++mt) {
          int ng = c*32 + mt*16 + an;
          const u16* hr = hbuf + ((size_t)(ng*512 + tprev) << 10) + dir*512 + kh*256;
#pragma unroll
          for (int kc = 0; kc < 8; ++kc) haf[mt][kc] = *(const v8s*)(hr + kc*32 + ak);
        }
        if constexpr (LAYER == 0) {
#pragma unroll
          for (int kc = 0; kc < 2; ++kc)
#pragma unroll
            for (int mt = 0; mt < 2; ++mt)
              acc[mt] = __builtin_amdgcn_mfma_f32_16x16x32_bf16(xreg[c][mt][kc], wih_reg[kc], acc[mt], 0,0,0);
        } else {
          v8s xaf[2][16];
#pragma unroll
          for (int mt = 0; mt < 2; ++mt) {
            int ng = c*32 + mt*16 + an;
            const u16* xr = xsrc + ((size_t)(ng*512 + t) << 10) + kh*512;
#pragma unroll
            for (int kc = 0; kc < 16; ++kc) xaf[mt][kc] = *(const v8s*)(xr + kc*32 + ak);
          }
#pragma unroll
          for (int kc = 0; kc < 16; ++kc)
#pragma unroll
            for (int mt = 0; mt < 2; ++mt)
              acc[mt] = __builtin_amdgcn_mfma_f32_16x16x32_bf16(xaf[mt][kc], wih_reg[kc], acc[mt], 0,0,0);
        }
#pragma unroll
        for (int kc = 0; kc < 8; ++kc)
#pragma unroll
          for (int mt = 0; mt < 2; ++mt)
            acc[mt] = __builtin_amdgcn_mfma_f32_16x16x32_bf16(haf[mt][kc], whh_reg[kc], acc[mt], 0,0,0);
      } else {
        if constexpr (LAYER == 0) {
#pragma unroll
          for (int kc = 0; kc < 2; ++kc)
#pragma unroll
            for (int mt = 0; mt < 2; ++mt)
              acc[mt] = __builtin_amdgcn_mfma_f32_16x16x32_bf16(xreg[c][mt][kc], wih_reg[kc], acc[mt], 0,0,0);
        } else {
          v8s xaf[2][16];
#pragma unroll
          for (int mt = 0; mt < 2; ++mt) {
            int ng = c*32 + mt*16 + an;
            const u16* xr = xsrc + ((size_t)(ng*512 + t) << 10) + kh*512;
#pragma unroll
            for (int kc = 0; kc < 16; ++kc) xaf[mt][kc] = *(const v8s*)(xr + kc*32 + ak);
          }
#pragma unroll
          for (int kc = 0; kc < 16; ++kc)
#pragma unroll
            for (int mt = 0; mt < 2; ++mt)
              acc[mt] = __builtin_amdgcn_mfma_f32_16x16x32_bf16(xaf[mt][kc], wih_reg[kc], acc[mt], 0,0,0);
        }
      }

      // ---- partial-gate exchange into this chain's glds ----
#pragma unroll
      for (int mt=0; mt<2; ++mt)
#pragma unroll
        for (int r=0; r<4; ++r) {
          int n = mt*16 + hi*4 + r;
          glds[c][((kh*4 + g)*32 + n)*10 + (an&7)] = acc[mt][r];
        }
      __syncthreads();

      // ---- pointwise (1 batch x 1 unit per thread) ----
      {
        float g0 = glds[c][(0*32+n2)*10+u_pw] + glds[c][(4*32+n2)*10+u_pw] + bsum[0];
        float g1 = glds[c][(1*32+n2)*10+u_pw] + glds[c][(5*32+n2)*10+u_pw] + bsum[1];
        float g2 = glds[c][(2*32+n2)*10+u_pw] + glds[c][(6*32+n2)*10+u_pw] + bsum[2];
        float g3 = glds[c][(3*32+n2)*10+u_pw] + glds[c][(7*32+n2)*10+u_pw] + bsum[3];
        float cn = sigm(g1)*creg[c] + sigm(g0)*ftanh(g2);
        creg[c] = cn;
        hlds[c][n2*8 + u_pw] = f2bf(sigm(g3)*ftanh(cn));
      }
      // rows n2 in [8w, 8w+8) were produced by THIS wave -> wave-local store,
      // no block sync (compiler orders LDS ops within the wave).
      if (lane < 8) {
        int nl = w*8 + lane;
        u64 a = *(const u64*)&hlds[c][nl*8];
        u64 b = *(const u64*)&hlds[c][nl*8 + 4];
        store_h16(hbuf + ((size_t)((c*32 + nl)*512 + t) << 10) + dir*512 + ug*8, a, b);
      }
    }

    // ---- L0: prefetch x for next step (drains with the stores) ----
    if constexpr (LAYER == 0) {
      if (step < 511) {
        const int tn = dir ? (t - 1) : (t + 1);
#pragma unroll
        for (int c = 0; c < 2; ++c)
#pragma unroll
          for (int mt = 0; mt < 2; ++mt) {
            int ng = c*32 + mt*16 + an;
            const u16* xr = xsrc + (size_t)Xidx[ng*512 + tn]*128 + kh*64;
#pragma unroll
            for (int kc = 0; kc < 2; ++kc) xreg[c][mt][kc] = *(const v8s*)(xr + kc*32 + ak);
          }
      }
    }

    asm volatile("s_waitcnt vmcnt(0)" ::: "memory");
    __syncthreads();   // all waves' WT stores ACKed at coherence point

    if (tid == 0)
      __hip_atomic_store(progA + ug, (unsigned)(step+1), __ATOMIC_RELAXED, __HIP_MEMORY_SCOPE_AGENT);
    if (tid == 1)
      __hip_atomic_store(progB + ug, (unsigned)(step+1), __ATOMIC_RELAXED, __HIP_MEMORY_SCOPE_AGENT);
  }
}

// ---------------------------------------------------------------------------
// Fused attention step
// ---------------------------------------------------------------------------
__global__ __launch_bounds__(256) void attn_step(
    const float* __restrict__ qbuf, const u16* __restrict__ Uah,
    const u16* __restrict__ hid, const int* __restrict__ seq_len,
    const u16* __restrict__ vaW, const u16* __restrict__ vab,
    u16* __restrict__ catb)
{
  int n = blockIdx.x, tid = threadIdx.x;
  __shared__ float qs[1024];
  __shared__ float vas[1024];
  __shared__ float es[512];
  __shared__ float red[8];
  for (int d=tid; d<1024; d+=256){ qs[d]=qbuf[n*1024+d]; vas[d]=bf2f(vaW[d]); }
  __syncthreads();
  int sl = seq_len[n];
  float vb = bf2f(vab[0]);
  for (int l=tid; l<512; l+=256) {
    const u16* up = Uah + ((size_t)n*512 + l)*1024;
    float a = 0.f;
    for (int d=0; d<1024; d+=8) {
      v8s uv = *(const v8s*)(up + d);
#pragma unroll
      for (int e=0;e<8;++e)
        a = fmaf(ftanh(bf2f((u16)uv[e]) + qs[d+e]), vas[d+e], a);
    }
    float ev = a + vb;
    if (l >= sl) ev += NEG_INF;
    es[l] = ev;
  }
  __syncthreads();
  float m = -3.4e38f;
  for (int l=tid; l<512; l+=256) m = fmaxf(m, es[l]);
#pragma unroll
  for (int off=1; off<64; off<<=1) m = fmaxf(m, __shfl_xor(m, off));
  if ((tid&63)==0) red[tid>>6] = m;
  __syncthreads();
  m = fmaxf(fmaxf(red[0],red[1]), fmaxf(red[2],red[3]));
  float s = 0.f;
  for (int l=tid; l<512; l+=256){ float p = __expf(es[l]-m); es[l]=p; s+=p; }
#pragma unroll
  for (int off=1; off<64; off<<=1) s += __shfl_xor(s, off);
  if ((tid&63)==0) red[4+(tid>>6)] = s;
  __syncthreads();
  float inv = 1.f/(red[4]+red[5]+red[6]+red[7]);
  int d0 = tid*4;
  float c0=0,c1=0,c2=0,c3=0;
  for (int l=0; l<512; ++l) {
    float a = es[l];
    const u16* hp = hid + ((size_t)n*512 + l)*1024 + d0;
    v4s hv = *(const v4s*)hp;
    c0 = fmaf(a, bf2f((u16)hv[0]), c0);
    c1 = fmaf(a, bf2f((u16)hv[1]), c1);
    c2 = fmaf(a, bf2f((u16)hv[2]), c2);
    c3 = fmaf(a, bf2f((u16)hv[3]), c3);
  }
  catb[n*2048 + d0 + 0] = f2bf(c0*inv);
  catb[n*2048 + d0 + 1] = f2bf(c1*inv);
  catb[n*2048 + d0 + 2] = f2bf(c2*inv);
  catb[n*2048 + d0 + 3] = f2bf(c3*inv);
}

__global__ void dec_pw(const float* __restrict__ g, u16* __restrict__ scat,
                       u16* __restrict__ catb, int it)
{
  int idx = blockIdx.x*256 + threadIdx.x;
  int n = idx >> 10, d = idx & 1023;
  float gi = g[(size_t)n*4096 + d];
  float gg = g[(size_t)n*4096 + 2048 + d];
  float go = g[(size_t)n*4096 + 3072 + d];
  float c = sigm(gi)*ftanh(gg);
  float s = sigm(go)*ftanh(c);
  u16 hb = f2bf(s);
  scat[((size_t)n*11 + it)*1024 + d] = hb;
  catb[n*2048 + 1024 + d] = hb;
}

__global__ void fill_sentinel(float* out, int nel){
  int i = blockIdx.x*256 + threadIdx.x;
  if (i < nel) out[i] = 12345.0f;
}

// ---------------------------------------------------------------------------
extern "C" void kernel_launch(void* const* d_in, const int* in_sizes, int n_in,
                              void* d_out, int out_size, void* d_ws, size_t ws_size,
                              hipStream_t stream)
{
  const int* X      = (const int*)d_in[0];
  const int* seqlen = (const int*)d_in[1];
  float* out = (float*)d_out;
  char* ws = (char*)d_ws;

  struct Seg { int idx; int n; };
  static const Seg segs[31] = {
    {2, 4096000},
    {3, 262144},{4,1048576},{5,2048},{6,2048},
    {7, 262144},{8,1048576},{9,2048},{10,2048},
    {11,2097152},{12,1048576},{13,2048},{14,2048},
    {15,2097152},{16,1048576},{17,2048},{18,2048},
    {19,1048576},{20,1024},
    {21,1048576},{22,1024},
    {23,1048576},{24,1024},
    {25,1024},{26,1},
    {27,4194304},{28,4194304},{29,4096},{30,4096},
    {31,10240000},{32,10000},
  };
  const u16* bp[33];
  CvtTab tab;
  size_t aoff = 0;
  for (int i = 0; i < 31; ++i) {
    bp[segs[i].idx] = (const u16*)(ws) + aoff;
    tab.src[i] = (const float*)d_in[segs[i].idx];
    tab.off[i] = (unsigned)aoff;
    tab.n[i]   = (unsigned)segs[i].n;
    aoff += (size_t)((segs[i].n + 7) & ~7);
  }
  tab.total = (unsigned)aoff;
  size_t arena_bytes = ((aoff*2 + 255) & ~(size_t)255);

  const size_t H0_OFF   = arena_bytes;
  const size_t HID_OFF  = H0_OFF   + 67108864;
  const size_t BAR_OFF  = HID_OFF  + 67108864;   // 16 KB progress words
  const size_t CATB_OFF = BAR_OFF  + 16384;
  const size_t QBUF_OFF = CATB_OFF + 262144;
  const size_t GDEC_OFF = QBUF_OFF + 262144;
  const size_t SCAT_OFF = GDEC_OFF + 1048576;
  const size_t NEED     = SCAT_OFF + 1441792;

  if (ws_size < NEED) {
    fill_sentinel<<<(out_size+255)/256, 256, 0, stream>>>(out, out_size);
    return;
  }

  u16*      h0   = (u16*)(ws + H0_OFF);
  u16*      Uah  = (u16*)(ws + H0_OFF);   // alias: h0 dead after encoder
  u16*      hid  = (u16*)(ws + HID_OFF);
  unsigned* bar  = (unsigned*)(ws + BAR_OFF);
  u16*      catb = (u16*)(ws + CATB_OFF);
  float*    qbuf = (float*)(ws + QBUF_OFF);
  float*    gdec = (float*)(ws + GDEC_OFF);
  u16*      scat = (u16*)(ws + SCAT_OFF);

  hipMemsetAsync(ws + BAR_OFF, 0, 16384, stream);

  {
    unsigned nth = (unsigned)(aoff / 8);
    cvt_all<<<(nth + 255)/256, 256, 0, stream>>>(tab, (u16*)ws);
  }

  // ---- encoder layer 0 (persistent scan, 2 chains/block) ----
  lstm_scan<0><<<128, 256, 0, stream>>>(
      bp[2], X, bp[3], bp[7], bp[4], bp[8],
      bp[5], bp[6], bp[9], bp[10], h0, bar);

  // ---- encoder layer 1 (separate progress region) ----
  lstm_scan<1><<<128, 256, 0, stream>>>(
      h0, nullptr, bp[11], bp[15], bp[12], bp[16],
      bp[13], bp[14], bp[17], bp[18], hid, bar + 1024);

  // ---- attention precompute ----
  gemm_bf16<<<dim3(256,8), 256, 0, stream>>>(hid, 1024, bp[23], bp[24], nullptr,
      Uah, 1024, 32768, 1024, 1024, GF_OUTBF16);
  gemm_bf16<<<dim3(1,8), 256, 0, stream>>>(hid, 524288, bp[19], bp[20], nullptr,
      catb + 1024, 2048, 64, 1024, 1024, GF_OUTBF16 | GF_TANH);

  // ---- 11 decoder steps ----
  for (int it = 0; it < 11; ++it) {
    gemm_bf16<<<dim3(1,8), 256, 0, stream>>>(catb + 1024, 2048, bp[21], bp[22], nullptr,
        qbuf, 1024, 64, 1024, 1024, 0);
    attn_step<<<64, 256, 0, stream>>>(qbuf, Uah, hid, seqlen, bp[25], bp[26], catb);
    gemm_bf16<<<dim3(1,32), 256, 0, stream>>>(catb, 2048, bp[27], bp[29], bp[30],
        gdec, 4096, 64, 4096, 1024, 0);
    gemm_bf16<<<dim3(1,32), 256, 0, stream>>>(catb + 1024, 2048, bp[28], nullptr, nullptr,
        gdec, 4096, 64, 4096, 1024, GF_ACCUM);
    dec_pw<<<256, 256, 0, stream>>>(gdec, scat, catb, it);
  }

  // ---- classifier (f32 output) ----
  gemm_bf16<<<dim3(6,79), 256, 0, stream>>>(scat, 1024, bp[31], bp[32], nullptr,
      out, 10000, 704, 10000, 1024, 0);
}

// Round 12
// 9494.827 us; speedup vs baseline: 1.6572x; 1.6572x over previous
//
#include <hip/hip_runtime.h>
#include <stdint.h>

#define NEG_INF -100000000.0f

typedef unsigned short u16;
typedef unsigned long long u64;
typedef __attribute__((ext_vector_type(8))) short v8s;
typedef __attribute__((ext_vector_type(4))) short v4s;
typedef __attribute__((ext_vector_type(4))) float v4f;

__device__ __forceinline__ float bf2f(u16 h){ return __uint_as_float(((unsigned)h)<<16); }
__device__ __forceinline__ u16 f2bf(float f){
  unsigned u = __float_as_uint(f);
  u = u + 0x7fffu + ((u>>16)&1u);
  return (u16)(u>>16);
}
__device__ __forceinline__ float sigm(float x){ return 1.0f/(1.0f+__expf(-x)); }
__device__ __forceinline__ float ftanh(float x){
  x = fminf(15.0f, fmaxf(-15.0f, x));
  float e = __expf(2.0f*x);
  return (e-1.0f)/(e+1.0f);
}

// write-through (coherence-point) 16B h store; consumer loads are PLAIN
__device__ __forceinline__ void store_h16(u16* p, u64 a, u64 b){
  __hip_atomic_store((u64*)p,     a, __ATOMIC_RELAXED, __HIP_MEMORY_SCOPE_AGENT);
  __hip_atomic_store((u64*)(p+4), b, __ATOMIC_RELAXED, __HIP_MEMORY_SCOPE_AGENT);
}

// ---------------------------------------------------------------------------
// Fused f32 -> bf16 arena conversion
// ---------------------------------------------------------------------------
struct CvtTab {
  const float* src[31];
  unsigned off[31];
  unsigned n[31];
  unsigned total;
};

__global__ __launch_bounds__(256) void cvt_all(CvtTab tab, u16* __restrict__ arena){
  unsigned e0 = (blockIdx.x*256u + threadIdx.x)*8u;
  if (e0 >= tab.total) return;
  int s = 0;
#pragma unroll 1
  for (int i = 1; i < 31; ++i) if (e0 >= tab.off[i]) s = i;
  unsigned rel = e0 - tab.off[s];
  const float* sp = tab.src[s] + rel;
  unsigned nn = tab.n[s];
  union { u16 h[8]; v8s v; } o;
  if (rel + 8 <= nn) {
    float4 a = *(const float4*)sp;
    float4 b = *(const float4*)(sp+4);
    o.h[0]=f2bf(a.x); o.h[1]=f2bf(a.y); o.h[2]=f2bf(a.z); o.h[3]=f2bf(a.w);
    o.h[4]=f2bf(b.x); o.h[5]=f2bf(b.y); o.h[6]=f2bf(b.z); o.h[7]=f2bf(b.w);
  } else {
#pragma unroll
    for (int k = 0; k < 8; ++k) o.h[k] = (rel + k < nn) ? f2bf(sp[k]) : (u16)0;
  }
  *(v8s*)(arena + e0) = o.v;
}

// concat [dec_Wih | dec_Whh] (bf16 arena) -> wcat [4096][2048]
__global__ void concat_w(const u16* __restrict__ wih, const u16* __restrict__ whh,
                         u16* __restrict__ outw)
{
  size_t i = (size_t)blockIdx.x*256 + threadIdx.x;  // 1M threads x 8 elems
  size_t p = i*8;
  int row = (int)(p >> 11); int k = (int)(p & 2047);
  v8s v = (k < 1024) ? *(const v8s*)(wih + (size_t)row*1024 + k)
                     : *(const v8s*)(whh + (size_t)row*1024 + (k-1024));
  *(v8s*)(outw + p) = v;
}

// ---------------------------------------------------------------------------
// Generic bf16 GEMM: C[M][N] = A[M][K] @ B[N][K]^T (+bias1+bias2)(+tanh)(+C)
// ---------------------------------------------------------------------------
#define GF_OUTBF16 1
#define GF_TANH    2
#define GF_ACCUM   4

__global__ __launch_bounds__(256) void gemm_bf16(
    const u16* __restrict__ A, long long lda,
    const u16* __restrict__ B,
    const u16* __restrict__ bias1, const u16* __restrict__ bias2,
    void* __restrict__ Cout, long long ldc,
    int M, int Nn, int K, int flags)
{
  __shared__ u16 As[8192];
  __shared__ u16 Bs[8192];
  int tid = threadIdx.x;
  int lane = tid & 63, w = tid >> 6;
  int wm = w >> 1, wn = w & 1;
  int bm = blockIdx.x * 128, bn = blockIdx.y * 128;

  v4f acc[4][4];
#pragma unroll
  for (int i=0;i<4;++i)
#pragma unroll
    for (int j=0;j<4;++j) acc[i][j] = (v4f){0.f,0.f,0.f,0.f};

#pragma unroll 1
  for (int ko = 0; ko < K; ko += 64) {
    __syncthreads();
#pragma unroll
    for (int it = 0; it < 8; ++it) {
      int c = tid + 256*it;
      int half = c >> 10;
      int cc = c & 1023;
      int r = cc >> 3;
      int kcb = cc & 7;
      const u16* src;
      if (half == 0) {
        int row = min(bm + r, M-1);
        src = A + (size_t)row*(size_t)lda + ko + (kcb<<3);
      } else {
        int row = min(bn + r, Nn-1);
        src = B + (size_t)row*(size_t)K + ko + (kcb<<3);
      }
      v8s v = *(const v8s*)src;
      char* base = (char*)(half ? Bs : As);
      *(v8s*)(base + (r<<7) + ((kcb<<4) ^ ((r&7)<<4))) = v;
    }
    __syncthreads();
#pragma unroll
    for (int ks = 0; ks < 2; ++ks) {
      v8s af[4], bfr[4];
#pragma unroll
      for (int mt=0; mt<4; ++mt) {
        int r = wm*64 + mt*16 + (lane & 15);
        int kb = (ks<<6) + ((lane>>4)<<4);
        af[mt] = *(const v8s*)((const char*)As + (r<<7) + (kb ^ ((r&7)<<4)));
      }
#pragma unroll
      for (int nt=0; nt<4; ++nt) {
        int r = wn*64 + nt*16 + (lane & 15);
        int kb = (ks<<6) + ((lane>>4)<<4);
        bfr[nt] = *(const v8s*)((const char*)Bs + (r<<7) + (kb ^ ((r&7)<<4)));
      }
#pragma unroll
      for (int mt=0; mt<4; ++mt)
#pragma unroll
        for (int nt=0; nt<4; ++nt)
          acc[mt][nt] = __builtin_amdgcn_mfma_f32_16x16x32_bf16(af[mt], bfr[nt], acc[mt][nt], 0,0,0);
    }
  }

#pragma unroll
  for (int mt=0; mt<4; ++mt) {
#pragma unroll
    for (int nt=0; nt<4; ++nt) {
      int col = bn + wn*64 + nt*16 + (lane&15);
      if (col >= Nn) continue;
      float b = 0.f;
      if (bias1) b += bf2f(bias1[col]);
      if (bias2) b += bf2f(bias2[col]);
#pragma unroll
      for (int r=0; r<4; ++r) {
        int row = bm + wm*64 + mt*16 + ((lane>>4)<<2) + r;
        if (row >= M) continue;
        float v = acc[mt][nt][r] + b;
        if (flags & GF_ACCUM) v += ((float*)Cout)[(size_t)row*(size_t)ldc + col];
        if (flags & GF_TANH) v = ftanh(v);
        if (flags & GF_OUTBF16) ((u16*)Cout)[(size_t)row*(size_t)ldc + col] = f2bf(v);
        else                    ((float*)Cout)[(size_t)row*(size_t)ldc + col] = v;
      }
    }
  }
}

// ---------------------------------------------------------------------------
// Persistent bidirectional LSTM scan (round-10 structure, byte-identical).
// 128 blocks = dir(2) x bg(2: 32 batches) x ug(32: 16 units); 4 independent
// groups of 32 blocks. Waves: kh = w>>1 (K-half), gp = w&1 (gate pair);
// MFMA N packs 2 gates x 8 units. Weights VGPR-pinned.
// Per-step schedule (2 syncthreads):
//   [x(s) already in regs]  poll(per-wave, 2 lines)  ->  issue h loads ->
//   x-MFMA (reg-only, hides h flight) -> h-MFMA -> glds exchange -> SYNC ->
//   pointwise -> hlds (wave-local rows) -> h store (same wave) ->
//   prefetch x(s+1) -> vmcnt(0) [stores & x-loads drain together] -> SYNC ->
//   progress store.
// Coherence: write-through relaxed-atomic h stores (LLC merge), plain
// consumer loads (lines written once, read only after progress seen).
// ---------------------------------------------------------------------------
template<int LAYER>
__global__ __launch_bounds__(256, 1) void lstm_scan(
    const u16* __restrict__ xsrc,      // L0: embW ; L1: h0
    const int* __restrict__ Xidx,      // L0 only
    const u16* __restrict__ Wih_f, const u16* __restrict__ Wih_b,
    const u16* __restrict__ Whh_f, const u16* __restrict__ Whh_b,
    const u16* __restrict__ bih_f, const u16* __restrict__ bhh_f,
    const u16* __restrict__ bih_b, const u16* __restrict__ bhh_b,
    u16* __restrict__ hbuf,            // [64][512][1024] layer output
    unsigned* __restrict__ prog)       // 4 groups x 32 u32 (2 lines each)
{
  constexpr int KX  = (LAYER==0) ? 128 : 1024;
  constexpr int NKC = KX/64;                 // x k-chunks per K-half (2 / 16)
  __shared__ float glds[8*32*18];            // [kh*4+gate][n(32)][u(16)+2pad]
  __shared__ u16   hlds[1024];               // [n(32)][u(16)]

  const int tid = threadIdx.x, lane = tid & 63, w = tid >> 6;
  const int kh = w >> 1, gp = w & 1;
  const int dir = blockIdx.x >> 6, bg = (blockIdx.x >> 5) & 1, ug = blockIdx.x & 31;
  const int an = lane & 15, hi = lane >> 4, ak = hi << 3;
  const u16* Wih = dir ? Wih_b : Wih_f;
  const u16* Whh = dir ? Whh_b : Whh_f;
  const int gid = dir*2 + bg;
  unsigned* gprog = prog + gid*32;           // 32 u32 = 128B = 2 lines

  const int g = 2*gp + (an>>3);              // gate for this lane's B-col

  // ---- weights pinned in VGPRs ----
  v8s wih_reg[2][NKC];
#pragma unroll
  for (int nt = 0; nt < 2; ++nt) {
    const u16* wp = Wih + ((size_t)g*512 + ug*16 + nt*8 + (an&7))*KX + kh*(KX/2);
#pragma unroll
    for (int kc = 0; kc < NKC; ++kc) {
      wih_reg[nt][kc] = *(const v8s*)(wp + kc*32 + ak);
      asm volatile("" : "+v"(wih_reg[nt][kc]));
    }
  }
  v8s whh_reg[2][8];
#pragma unroll
  for (int nt = 0; nt < 2; ++nt) {
    const u16* wp = Whh + ((size_t)g*512 + ug*16 + nt*8 + (an&7))*512 + kh*256;
#pragma unroll
    for (int kc = 0; kc < 8; ++kc) {
      whh_reg[nt][kc] = *(const v8s*)(wp + kc*32 + ak);
      asm volatile("" : "+v"(whh_reg[nt][kc]));
    }
  }

  const int u_pw = tid & 15, n2 = tid >> 4;  // pointwise: unit u_pw, rows n2, n2+16
  const int uj_pw = ug*16 + u_pw;
  float bsum[4];
  {
    const u16* bi = dir ? bih_b : bih_f;
    const u16* bh = dir ? bhh_b : bhh_f;
#pragma unroll
    for (int q = 0; q < 4; ++q)
      bsum[q] = bf2f(bi[q*512 + uj_pw]) + bf2f(bh[q*512 + uj_pw]);
  }
  float creg[2] = {0.f, 0.f};

  // ---- x prefetch registers: load step 0 ----
  v8s xreg[2][NKC];
  {
    const int t0 = dir ? 511 : 0;
#pragma unroll
    for (int mt = 0; mt < 2; ++mt) {
      int ng = bg*32 + mt*16 + an;
      const u16* xr;
      if constexpr (LAYER == 0) xr = xsrc + (size_t)Xidx[ng*512 + t0]*128 + kh*64;
      else                      xr = xsrc + ((size_t)(ng*512 + t0) << 10) + kh*512;
#pragma unroll
      for (int kc = 0; kc < NKC; ++kc) xreg[mt][kc] = *(const v8s*)(xr + kc*32 + ak);
    }
  }

  for (int step = 0; step < 512; ++step) {
    const int t     = dir ? (511 - step) : step;
    const int tprev = dir ? (t + 1) : (t - 1);

    v4f acc[2][2];
#pragma unroll
    for (int i=0;i<2;++i){ acc[i][0]=(v4f){0,0,0,0}; acc[i][1]=(v4f){0,0,0,0}; }

    if (step > 0) {
      // ---- per-wave poll (2 packed lines, spin-first) ----
      {
        const u64* pl = (const u64*)gprog;
        int spins = 0;
        for (;;) {
          u64 v = ~0ull;
          if (lane < 16)
            v = __hip_atomic_load(pl + lane, __ATOMIC_RELAXED, __HIP_MEMORY_SCOPE_AGENT);
          bool ok = ((unsigned)v >= (unsigned)step) && ((unsigned)(v>>32) >= (unsigned)step);
          if (__all(ok)) break;
          if (++spins > 4) __builtin_amdgcn_s_sleep(1);
        }
        asm volatile("" ::: "memory");
      }

      // ---- issue h loads first; x-MFMA (register-only) hides their flight ----
      v8s haf[2][8];
#pragma unroll
      for (int mt = 0; mt < 2; ++mt) {
        int ng = bg*32 + mt*16 + an;
        const u16* hr = hbuf + ((size_t)(ng*512 + tprev) << 10) + dir*512 + kh*256;
#pragma unroll
        for (int kc = 0; kc < 8; ++kc) haf[mt][kc] = *(const v8s*)(hr + kc*32 + ak);
      }
#pragma unroll
      for (int kc = 0; kc < NKC; ++kc)
#pragma unroll
        for (int nt = 0; nt < 2; ++nt)
#pragma unroll
          for (int mt = 0; mt < 2; ++mt)
            acc[mt][nt] = __builtin_amdgcn_mfma_f32_16x16x32_bf16(xreg[mt][kc], wih_reg[nt][kc], acc[mt][nt], 0,0,0);
#pragma unroll
      for (int kc = 0; kc < 8; ++kc)
#pragma unroll
        for (int nt = 0; nt < 2; ++nt)
#pragma unroll
          for (int mt = 0; mt < 2; ++mt)
            acc[mt][nt] = __builtin_amdgcn_mfma_f32_16x16x32_bf16(haf[mt][kc], whh_reg[nt][kc], acc[mt][nt], 0,0,0);
    } else {
#pragma unroll
      for (int kc = 0; kc < NKC; ++kc)
#pragma unroll
        for (int nt = 0; nt < 2; ++nt)
#pragma unroll
          for (int mt = 0; mt < 2; ++mt)
            acc[mt][nt] = __builtin_amdgcn_mfma_f32_16x16x32_bf16(xreg[mt][kc], wih_reg[nt][kc], acc[mt][nt], 0,0,0);
    }

    // ---- partial-gate exchange: slice = kh*4+gate, row n(32), col u(16) ----
#pragma unroll
    for (int mt=0; mt<2; ++mt)
#pragma unroll
      for (int nt=0; nt<2; ++nt)
#pragma unroll
        for (int r=0; r<4; ++r) {
          int n = mt*16 + hi*4 + r;
          int u = nt*8 + (an&7);
          glds[((kh*4 + g)*32 + n)*18 + u] = acc[mt][nt][r];
        }
    __syncthreads();

    // ---- pointwise: sum both K-half partials + biases (rows n2, n2+16) ----
#pragma unroll
    for (int k = 0; k < 2; ++k) {
      int n = k*16 + n2;
      float g0 = glds[(0*32+n)*18+u_pw] + glds[(4*32+n)*18+u_pw] + bsum[0];
      float g1 = glds[(1*32+n)*18+u_pw] + glds[(5*32+n)*18+u_pw] + bsum[1];
      float g2 = glds[(2*32+n)*18+u_pw] + glds[(6*32+n)*18+u_pw] + bsum[2];
      float g3 = glds[(3*32+n)*18+u_pw] + glds[(7*32+n)*18+u_pw] + bsum[3];
      float cn = sigm(g1)*creg[k] + sigm(g0)*ftanh(g2);
      creg[k] = cn;
      hlds[n*16 + u_pw] = f2bf(sigm(g3)*ftanh(cn));
    }
    // rows {4w..4w+3, 16+4w..19+4w} were written by THIS wave -> no block sync;
    // compiler inserts lgkmcnt before the dependent LDS reads below.

    // ---- wave-local packed write-through h store (8 lines per wave) ----
    if (lane < 16) {
      int j = lane >> 1;
      int n = 4*w + (j & 3) + 16*(j >> 2);
      int half = lane & 1;
      u64 a = *(const u64*)&hlds[n*16 + half*8];
      u64 b = *(const u64*)&hlds[n*16 + half*8 + 4];
      store_h16(hbuf + ((size_t)((bg*32+n)*512 + t) << 10) + dir*512 + ug*16 + half*8, a, b);
    }

    // ---- prefetch x for next step (drains together with the stores) ----
    if (step < 511) {
      const int tn = dir ? (t - 1) : (t + 1);
#pragma unroll
      for (int mt = 0; mt < 2; ++mt) {
        int ng = bg*32 + mt*16 + an;
        const u16* xr;
        if constexpr (LAYER == 0) xr = xsrc + (size_t)Xidx[ng*512 + tn]*128 + kh*64;
        else                      xr = xsrc + ((size_t)(ng*512 + tn) << 10) + kh*512;
#pragma unroll
        for (int kc = 0; kc < NKC; ++kc) xreg[mt][kc] = *(const v8s*)(xr + kc*32 + ak);
      }
    }

    asm volatile("s_waitcnt vmcnt(0)" ::: "memory");
    __syncthreads();   // all waves' stores ACKed at coherence point

    if (tid == 0)
      __hip_atomic_store(gprog + ug, (unsigned)(step+1), __ATOMIC_RELAXED, __HIP_MEMORY_SCOPE_AGENT);
  }
}

// ---------------------------------------------------------------------------
// Fused attention step
// ---------------------------------------------------------------------------
__global__ __launch_bounds__(256) void attn_step(
    const float* __restrict__ qbuf, const u16* __restrict__ Uah,
    const u16* __restrict__ hid, const int* __restrict__ seq_len,
    const u16* __restrict__ vaW, const u16* __restrict__ vab,
    u16* __restrict__ catb)
{
  int n = blockIdx.x, tid = threadIdx.x;
  __shared__ float qs[1024];
  __shared__ float vas[1024];
  __shared__ float es[512];
  __shared__ float red[8];
  for (int d=tid; d<1024; d+=256){ qs[d]=qbuf[n*1024+d]; vas[d]=bf2f(vaW[d]); }
  __syncthreads();
  int sl = seq_len[n];
  float vb = bf2f(vab[0]);
  for (int l=tid; l<512; l+=256) {
    const u16* up = Uah + ((size_t)n*512 + l)*1024;
    float a = 0.f;
    for (int d=0; d<1024; d+=8) {
      v8s uv = *(const v8s*)(up + d);
#pragma unroll
      for (int e=0;e<8;++e)
        a = fmaf(ftanh(bf2f((u16)uv[e]) + qs[d+e]), vas[d+e], a);
    }
    float ev = a + vb;
    if (l >= sl) ev += NEG_INF;
    es[l] = ev;
  }
  __syncthreads();
  float m = -3.4e38f;
  for (int l=tid; l<512; l+=256) m = fmaxf(m, es[l]);
#pragma unroll
  for (int off=1; off<64; off<<=1) m = fmaxf(m, __shfl_xor(m, off));
  if ((tid&63)==0) red[tid>>6] = m;
  __syncthreads();
  m = fmaxf(fmaxf(red[0],red[1]), fmaxf(red[2],red[3]));
  float s = 0.f;
  for (int l=tid; l<512; l+=256){ float p = __expf(es[l]-m); es[l]=p; s+=p; }
#pragma unroll
  for (int off=1; off<64; off<<=1) s += __shfl_xor(s, off);
  if ((tid&63)==0) red[4+(tid>>6)] = s;
  __syncthreads();
  float inv = 1.f/(red[4]+red[5]+red[6]+red[7]);
  int d0 = tid*4;
  float c0=0,c1=0,c2=0,c3=0;
  for (int l=0; l<512; ++l) {
    float a = es[l];
    const u16* hp = hid + ((size_t)n*512 + l)*1024 + d0;
    v4s hv = *(const v4s*)hp;
    c0 = fmaf(a, bf2f((u16)hv[0]), c0);
    c1 = fmaf(a, bf2f((u16)hv[1]), c1);
    c2 = fmaf(a, bf2f((u16)hv[2]), c2);
    c3 = fmaf(a, bf2f((u16)hv[3]), c3);
  }
  catb[n*2048 + d0 + 0] = f2bf(c0*inv);
  catb[n*2048 + d0 + 1] = f2bf(c1*inv);
  catb[n*2048 + d0 + 2] = f2bf(c2*inv);
  catb[n*2048 + d0 + 3] = f2bf(c3*inv);
}

__global__ void dec_pw(const float* __restrict__ g, u16* __restrict__ scat,
                       u16* __restrict__ catb, int it)
{
  int idx = blockIdx.x*256 + threadIdx.x;
  int n = idx >> 10, d = idx & 1023;
  float gi = g[(size_t)n*4096 + d];
  float gg = g[(size_t)n*4096 + 2048 + d];
  float go = g[(size_t)n*4096 + 3072 + d];
  float c = sigm(gi)*ftanh(gg);
  float s = sigm(go)*ftanh(c);
  u16 hb = f2bf(s);
  scat[((size_t)n*11 + it)*1024 + d] = hb;
  catb[n*2048 + 1024 + d] = hb;
}

__global__ void fill_sentinel(float* out, int nel){
  int i = blockIdx.x*256 + threadIdx.x;
  if (i < nel) out[i] = 12345.0f;
}

// ---------------------------------------------------------------------------
extern "C" void kernel_launch(void* const* d_in, const int* in_sizes, int n_in,
                              void* d_out, int out_size, void* d_ws, size_t ws_size,
                              hipStream_t stream)
{
  const int* X      = (const int*)d_in[0];
  const int* seqlen = (const int*)d_in[1];
  float* out = (float*)d_out;
  char* ws = (char*)d_ws;

  struct Seg { int idx; int n; };
  static const Seg segs[31] = {
    {2, 4096000},
    {3, 262144},{4,1048576},{5,2048},{6,2048},
    {7, 262144},{8,1048576},{9,2048},{10,2048},
    {11,2097152},{12,1048576},{13,2048},{14,2048},
    {15,2097152},{16,1048576},{17,2048},{18,2048},
    {19,1048576},{20,1024},
    {21,1048576},{22,1024},
    {23,1048576},{24,1024},
    {25,1024},{26,1},
    {27,4194304},{28,4194304},{29,4096},{30,4096},
    {31,10240000},{32,10000},
  };
  const u16* bp[33];
  CvtTab tab;
  size_t aoff = 0;
  for (int i = 0; i < 31; ++i) {
    bp[segs[i].idx] = (const u16*)(ws) + aoff;
    tab.src[i] = (const float*)d_in[segs[i].idx];
    tab.off[i] = (unsigned)aoff;
    tab.n[i]   = (unsigned)segs[i].n;
    aoff += (size_t)((segs[i].n + 7) & ~7);
  }
  tab.total = (unsigned)aoff;
  size_t arena_bytes = ((aoff*2 + 255) & ~(size_t)255);

  const size_t H0_OFF   = arena_bytes;
  const size_t HID_OFF  = H0_OFF   + 67108864;
  const size_t BAR_OFF  = HID_OFF  + 67108864;   // 16 KB progress words
  const size_t CATB_OFF = BAR_OFF  + 16384;
  const size_t QBUF_OFF = CATB_OFF + 262144;
  const size_t GDEC_OFF = QBUF_OFF + 262144;
  const size_t SCAT_OFF = GDEC_OFF + 1048576;
  const size_t WCAT_OFF = SCAT_OFF + 1441792;    // [4096][2048] bf16 = 16MB
  const size_t NEED     = WCAT_OFF + 16777216;   // ~217 MB (ws proven >= 221 MB)

  if (ws_size < NEED) {
    fill_sentinel<<<(out_size+255)/256, 256, 0, stream>>>(out, out_size);
    return;
  }

  u16*      h0   = (u16*)(ws + H0_OFF);
  u16*      Uah  = (u16*)(ws + H0_OFF);   // alias: h0 dead after encoder
  u16*      hid  = (u16*)(ws + HID_OFF);
  unsigned* bar  = (unsigned*)(ws + BAR_OFF);
  u16*      catb = (u16*)(ws + CATB_OFF);
  float*    qbuf = (float*)(ws + QBUF_OFF);
  float*    gdec = (float*)(ws + GDEC_OFF);
  u16*      scat = (u16*)(ws + SCAT_OFF);
  u16*      wcat = (u16*)(ws + WCAT_OFF);

  hipMemsetAsync(ws + BAR_OFF, 0, 16384, stream);

  {
    unsigned nth = (unsigned)(aoff / 8);
    cvt_all<<<(nth + 255)/256, 256, 0, stream>>>(tab, (u16*)ws);
  }
  concat_w<<<4096, 256, 0, stream>>>(bp[27], bp[28], wcat);

  // ---- encoder layer 0 (persistent scan) ----
  lstm_scan<0><<<128, 256, 0, stream>>>(
      bp[2], X, bp[3], bp[7], bp[4], bp[8],
      bp[5], bp[6], bp[9], bp[10], h0, bar);

  // ---- encoder layer 1 (separate progress region) ----
  lstm_scan<1><<<128, 256, 0, stream>>>(
      h0, nullptr, bp[11], bp[15], bp[12], bp[16],
      bp[13], bp[14], bp[17], bp[18], hid, bar + 1024);

  // ---- attention precompute ----
  gemm_bf16<<<dim3(256,8), 256, 0, stream>>>(hid, 1024, bp[23], bp[24], nullptr,
      Uah, 1024, 32768, 1024, 1024, GF_OUTBF16);
  gemm_bf16<<<dim3(1,8), 256, 0, stream>>>(hid, 524288, bp[19], bp[20], nullptr,
      catb + 1024, 2048, 64, 1024, 1024, GF_OUTBF16 | GF_TANH);

  // ---- 11 decoder steps (fused K=2048 gate GEMM) ----
  for (int it = 0; it < 11; ++it) {
    gemm_bf16<<<dim3(1,8), 256, 0, stream>>>(catb + 1024, 2048, bp[21], bp[22], nullptr,
        qbuf, 1024, 64, 1024, 1024, 0);
    attn_step<<<64, 256, 0, stream>>>(qbuf, Uah, hid, seqlen, bp[25], bp[26], catb);
    gemm_bf16<<<dim3(1,32), 256, 0, stream>>>(catb, 2048, wcat, bp[29], bp[30],
        gdec, 4096, 64, 4096, 2048, 0);
    dec_pw<<<256, 256, 0, stream>>>(gdec, scat, catb, it);
  }

  // ---- classifier (f32 output) ----
  gemm_bf16<<<dim3(6,79), 256, 0, stream>>>(scat, 1024, bp[31], bp[32], nullptr,
      out, 10000, 704, 10000, 1024, 0);
}